// Round 23
// baseline (165.295 us; speedup 1.0000x reference)
//
#include <hip/hip_runtime.h>
#include <hip/hip_bf16.h>
#include <cstdint>
#include <cstddef>

// Problem constants
#define NB 64
#define NK 49
#define NT 512
#define NH 512
#define NA 49

typedef __attribute__((ext_vector_type(8))) short bf16x8;
typedef __attribute__((ext_vector_type(4))) float f32x4;

__device__ __forceinline__ float fast_exp(float x) {            // e^x
    return __builtin_amdgcn_exp2f(x * 1.4426950408889634f);
}
__device__ __forceinline__ float fast_tanh(float x) {           // 1 - 2/(e^{2x}+1)
    float e = __builtin_amdgcn_exp2f(x * 2.8853900817779268f);
    return 1.0f - 2.0f * __builtin_amdgcn_rcpf(e + 1.0f);
}
__device__ __forceinline__ short bf16rn(float x) {              // round-to-nearest-even bf16
    unsigned b = __builtin_bit_cast(unsigned, x);
    unsigned r = b + 0x7FFFu + ((b >> 16) & 1u);
    return (short)(r >> 16);
}
__device__ __forceinline__ void split_hi_lo(float x, short& hi, short& lo) {
    unsigned b = __builtin_bit_cast(unsigned, x);
    unsigned hb = b & 0xFFFF0000u;
    hi = (short)(hb >> 16);
    lo = bf16rn(x - __builtin_bit_cast(float, hb));
}
__device__ __forceinline__ bf16x8 cvt8(float4 x0, float4 x1) {  // 8 f32 -> bf16 (rn)
    bf16x8 a;
    a[0] = bf16rn(x0.x); a[1] = bf16rn(x0.y); a[2] = bf16rn(x0.z); a[3] = bf16rn(x0.w);
    a[4] = bf16rn(x1.x); a[5] = bf16rn(x1.y); a[6] = bf16rn(x1.z); a[7] = bf16rn(x1.w);
    return a;
}

// ---------------------------------------------------------------------------
// kprew: weight swizzle (producer of WB; separate launch for ordering).
// WB[job][sel(hi/lo)][ntile(4)][kstep(16)][lane(64)][e(8)] (bf16)
// jobs 0/1: sel=0 is rn-rounded (single-term consumer in kfused).
// job 2:    sel=0 truncated hi, sel=1 lo (3-term consumer in kprev).
// ---------------------------------------------------------------------------
__global__ __launch_bounds__(256, 4) void kprew(
        const float* __restrict__ Wg, const float* __restrict__ Ws,
        const float* __restrict__ Wv, short* __restrict__ WB) {
    const int job = blockIdx.x >> 3, slice = blockIdx.x & 7;
    const float* W = (job == 0) ? Wg : (job == 1 ? Ws : Wv);
    short* dst = WB + (size_t)job * 65536;
    const int end = (slice + 1) * 8192;
    for (int idx = slice * 8192 + threadIdx.x; idx < end; idx += 256) {
        int e    = idx & 7;
        int lane = (idx >> 3) & 63;
        int ks   = (idx >> 9) & 15;
        int nt   = (idx >> 13) & 3;
        int sel  = idx >> 15;
        int a = nt * 16 + (lane & 15);
        int h = ks * 32 + (lane >> 4) * 8 + e;
        float x = (a < NA) ? W[a * NH + h] : 0.0f;
        short v;
        if (job < 2) {
            short hi, lo; split_hi_lo(x, hi, lo);
            v = sel ? lo : bf16rn(x);
        } else {
            short hi, lo; split_hi_lo(x, hi, lo);
            v = sel ? lo : hi;
        }
        dst[idx] = v;
    }
}

// ---------------------------------------------------------------------------
// kprev: blocks 0..511 = V frag swizzle; blocks 512..560 = cv GEMM (reads WB
// from previous launch; hi/lo 3-term kept for cv precision).
//  VB[b][ntile(32)][ks(2)][lane(64)][e(8)]; cv rows padded to 52 floats.
// ---------------------------------------------------------------------------
__global__ __launch_bounds__(256, 4) void kprev(
        const float* __restrict__ V, const short* __restrict__ WB,
        short* __restrict__ VB, float* __restrict__ cv) {
    const int bid = blockIdx.x;
    if (bid < 512) {
        __shared__ float vl[NK * 64];
        const int b  = bid >> 3;
        const int sl = bid & 7;
        const int h0 = sl * 64;
        const float* Vb = V + (size_t)b * (NK * NH);
        for (int idx = threadIdx.x; idx < NK * 64; idx += 256) {
            int k = idx >> 6, c = idx & 63;
            vl[idx] = Vb[(size_t)k * NH + h0 + c];
        }
        __syncthreads();
        short* dst = VB + (size_t)b * 32768;
        for (int idx = threadIdx.x; idx < 4096; idx += 256) {
            int e    = idx & 7;
            int lane = (idx >> 3) & 63;
            int ks   = (idx >> 9) & 1;
            int ntl  = idx >> 10;
            int k = ks * 32 + (lane >> 4) * 8 + e;
            int c = ntl * 16 + (lane & 15);
            float x = (k < NK) ? vl[k * 64 + c] : 0.0f;
            dst[((size_t)(sl * 4 + ntl) * 2 + ks) * 512 + lane * 8 + e] = bf16rn(x);
        }
    } else {
        const int tid  = threadIdx.x;
        const int lane = tid & 63;
        const int w    = tid >> 6;
        const int m0   = (bid - 512) * 64 + w * 16;
        const int r    = lane & 15;
        const int g    = lane >> 4;

        const float* arow = V + (size_t)(m0 + r) * NH + g * 8;
        const bf16x8* wbv = (const bf16x8*)(WB + 2 * 65536);

        f32x4 acc0 = {0.f, 0.f, 0.f, 0.f};
        f32x4 acc1 = acc0, acc2 = acc0, acc3 = acc0;

        #pragma unroll 2
        for (int ks = 0; ks < 16; ++ks) {
            float4 x0 = *(const float4*)(arow + ks * 32);
            float4 x1 = *(const float4*)(arow + ks * 32 + 4);
            bf16x8 bh0 = wbv[(0 * 16 + ks) * 64 + lane];
            bf16x8 bh1 = wbv[(1 * 16 + ks) * 64 + lane];
            bf16x8 bh2 = wbv[(2 * 16 + ks) * 64 + lane];
            bf16x8 bh3 = wbv[(3 * 16 + ks) * 64 + lane];
            bf16x8 bl0 = wbv[(4 * 16 + ks) * 64 + lane];
            bf16x8 bl1 = wbv[(5 * 16 + ks) * 64 + lane];
            bf16x8 bl2 = wbv[(6 * 16 + ks) * 64 + lane];
            bf16x8 bl3 = wbv[(7 * 16 + ks) * 64 + lane];

            bf16x8 ahi, alo;
            {
                const float xs[8] = {x0.x, x0.y, x0.z, x0.w, x1.x, x1.y, x1.z, x1.w};
                #pragma unroll
                for (int e = 0; e < 8; ++e) { short hi, lo; split_hi_lo(xs[e], hi, lo); ahi[e] = hi; alo[e] = lo; }
            }
            acc0 = __builtin_amdgcn_mfma_f32_16x16x32_bf16(ahi, bh0, acc0, 0, 0, 0);
            acc0 = __builtin_amdgcn_mfma_f32_16x16x32_bf16(alo, bh0, acc0, 0, 0, 0);
            acc0 = __builtin_amdgcn_mfma_f32_16x16x32_bf16(ahi, bl0, acc0, 0, 0, 0);
            acc1 = __builtin_amdgcn_mfma_f32_16x16x32_bf16(ahi, bh1, acc1, 0, 0, 0);
            acc1 = __builtin_amdgcn_mfma_f32_16x16x32_bf16(alo, bh1, acc1, 0, 0, 0);
            acc1 = __builtin_amdgcn_mfma_f32_16x16x32_bf16(ahi, bl1, acc1, 0, 0, 0);
            acc2 = __builtin_amdgcn_mfma_f32_16x16x32_bf16(ahi, bh2, acc2, 0, 0, 0);
            acc2 = __builtin_amdgcn_mfma_f32_16x16x32_bf16(alo, bh2, acc2, 0, 0, 0);
            acc2 = __builtin_amdgcn_mfma_f32_16x16x32_bf16(ahi, bl2, acc2, 0, 0, 0);
            acc3 = __builtin_amdgcn_mfma_f32_16x16x32_bf16(ahi, bh3, acc3, 0, 0, 0);
            acc3 = __builtin_amdgcn_mfma_f32_16x16x32_bf16(alo, bh3, acc3, 0, 0, 0);
            acc3 = __builtin_amdgcn_mfma_f32_16x16x32_bf16(ahi, bl3, acc3, 0, 0, 0);
        }

        #pragma unroll
        for (int reg = 0; reg < 4; ++reg) {
            int row = m0 + g * 4 + reg;
            float* orow = cv + (size_t)row * 52;
            orow[ 0 + r] = acc0[reg];
            orow[16 + r] = acc1[reg];
            orow[32 + r] = acc2[reg];
            if (r == 0) orow[48] = acc3[reg];
        }
    }
}

// ---------------------------------------------------------------------------
// kfused (R22 + fused BC, barrier removed): one block per (b, 32-row t-tile).
// 256 threads = 4 waves. 1024 blocks. XCD swizzle (R22-proven, -17MB FETCH).
//  A) gh/ss MFMA GEMM -> LDS. SINGLE-bf16 A and B; ks-PAIR hoisted loads.
//  BC) FUSED (no barrier): 8-lane group owns t-row; computes its own z slots
//      (writer==reader lane), in-register running max, shfl softmax, sentinel,
//      beta; alpha -> zl (own slots) + afrag LDS. Global alpha stays in the
//      SEPARATE COALESCED pass (R15: scattered global alpha RMW-amplifies).
//  D) c_t = alpha x V (single-bf16 MFMA), blend with s_t, store
// launch_bounds(256,4) = 128 total VGPR (only non-spilling bound). No
// cross-phase register state (R13/R20 spilled).
// ---------------------------------------------------------------------------
__global__ __launch_bounds__(256, 4) void kfused(
        const float* __restrict__ h_t, const float* __restrict__ s_t,
        const float* __restrict__ Wh,
        const short* __restrict__ WB, const short* __restrict__ VB,
        const float* __restrict__ cv_ws,
        float* __restrict__ out_chat, float* __restrict__ out_alpha,
        float* __restrict__ out_beta) {
    __shared__ float cvl[NK * 52];       // 10,192 B (padded rows, direct copy)
    __shared__ float ghl[32 * 52];       //  6,656 B
    __shared__ float ssl[32 * 52];       //  6,656 B
    __shared__ float zl[32 * 50];        //  6,400 B ; alpha fp32 overlays
    __shared__ short afrag[2048];        //  4,096 B : [ks(2)][mt(2)][lane(64)][e(8)]
    __shared__ float whl[52];            //    208 B
    __shared__ float betal[32];          //    128 B

    const int tid  = threadIdx.x;
    const int lane = tid & 63;
    const int w    = tid >> 6;
    // XCD-aware swizzle: same-b blocks cluster on one XCD (L2 locality).
    const int bid  = ((blockIdx.x & 7) << 7) + (blockIdx.x >> 3);
    const int b    = bid >> 4;
    const int t0   = (bid & 15) * 32;
    const int r    = lane & 15;
    const int g    = lane >> 4;

    if (tid < NA) whl[tid] = Wh[tid];

    // ---- stage cv (padded-52 rows, contiguous coalesced copy)
    {
        const float* cvb = cv_ws + (size_t)b * (NK * 52);
        for (int idx = tid; idx < NK * 52; idx += 256) cvl[idx] = cvb[idx];
    }

    // ---- phase A: gh / ss GEMM, single-bf16 both sides, ks-pair hoisted.
    {
        const int job = w >> 1, mtile = w & 1;
        const float* in = job ? s_t : h_t;
        const bf16x8* wb = (const bf16x8*)(WB + (size_t)job * 65536);
        const float* arow = in + (size_t)(b * NT + t0 + mtile * 16 + r) * NH + g * 8;
        f32x4 acc0 = {0.f, 0.f, 0.f, 0.f};
        f32x4 acc1 = acc0, acc2 = acc0, acc3 = acc0;
        #pragma unroll 1
        for (int kp = 0; kp < 8; ++kp) {
            const int ksa = kp * 2, ksb = kp * 2 + 1;
            // ---- all loads for both ks of the pair issue first (MLP)
            float4 xa0 = *(const float4*)(arow + ksa * 32);
            float4 xa1 = *(const float4*)(arow + ksa * 32 + 4);
            float4 xb0 = *(const float4*)(arow + ksb * 32);
            float4 xb1 = *(const float4*)(arow + ksb * 32 + 4);
            bf16x8 b0a = wb[(0 * 16 + ksa) * 64 + lane];
            bf16x8 b1a = wb[(1 * 16 + ksa) * 64 + lane];
            bf16x8 b2a = wb[(2 * 16 + ksa) * 64 + lane];
            bf16x8 b3a = wb[(3 * 16 + ksa) * 64 + lane];
            bf16x8 b0b = wb[(0 * 16 + ksb) * 64 + lane];
            bf16x8 b1b = wb[(1 * 16 + ksb) * 64 + lane];
            bf16x8 b2b = wb[(2 * 16 + ksb) * 64 + lane];
            bf16x8 b3b = wb[(3 * 16 + ksb) * 64 + lane];

            bf16x8 aa = cvt8(xa0, xa1);
            acc0 = __builtin_amdgcn_mfma_f32_16x16x32_bf16(aa, b0a, acc0, 0, 0, 0);
            acc1 = __builtin_amdgcn_mfma_f32_16x16x32_bf16(aa, b1a, acc1, 0, 0, 0);
            acc2 = __builtin_amdgcn_mfma_f32_16x16x32_bf16(aa, b2a, acc2, 0, 0, 0);
            acc3 = __builtin_amdgcn_mfma_f32_16x16x32_bf16(aa, b3a, acc3, 0, 0, 0);

            bf16x8 ab = cvt8(xb0, xb1);
            acc0 = __builtin_amdgcn_mfma_f32_16x16x32_bf16(ab, b0b, acc0, 0, 0, 0);
            acc1 = __builtin_amdgcn_mfma_f32_16x16x32_bf16(ab, b1b, acc1, 0, 0, 0);
            acc2 = __builtin_amdgcn_mfma_f32_16x16x32_bf16(ab, b2b, acc2, 0, 0, 0);
            acc3 = __builtin_amdgcn_mfma_f32_16x16x32_bf16(ab, b3b, acc3, 0, 0, 0);
        }
        float* dst = (w >> 1) ? ssl : ghl;
        #pragma unroll
        for (int reg = 0; reg < 4; ++reg) {
            int m = mtile * 16 + g * 4 + reg;
            dst[m * 52 +  0 + r] = acc0[reg];
            dst[m * 52 + 16 + r] = acc1[reg];
            dst[m * 52 + 32 + r] = acc2[reg];
            if (r < 4) dst[m * 52 + 48 + r] = acc3[reg];  // only col 48 used downstream
        }
    }
    __syncthreads();   // barrier #1: cvl/ghl/ssl ready

    // ---- fused BC: 8-lane group owns t-row trow; no barrier inside.
    // Lane (w, lane): trow = 8w + (lane>>3), sub = lane&7. z into OWN zl
    // slots (writer==reader), running max in-register.
    {
        const int trow = w * 8 + (lane >> 3);
        const int sub  = lane & 7;
        const float* gp = ghl + trow * 52;
        float* zr = zl + trow * 50;

        float m = -1e30f;
        for (int k = sub; k < NK; k += 8) {
            const float* rowp = cvl + k * 52;
            float zx = 0.f, zy = 0.f, zz = 0.f, zw = 0.f;
            #pragma unroll
            for (int q = 0; q < 12; ++q) {
                float4 rr = *(const float4*)(rowp + q * 4);
                float4 gg = *(const float4*)(gp + q * 4);
                zx = fmaf(whl[q * 4 + 0], fast_tanh(rr.x + gg.x), zx);
                zy = fmaf(whl[q * 4 + 1], fast_tanh(rr.y + gg.y), zy);
                zz = fmaf(whl[q * 4 + 2], fast_tanh(rr.z + gg.z), zz);
                zw = fmaf(whl[q * 4 + 3], fast_tanh(rr.w + gg.w), zw);
            }
            float z = (zx + zy) + (zz + zw);
            z = fmaf(whl[48], fast_tanh(rowp[48] + gp[48]), z);
            zr[k] = z;                     // own slot; re-read by same lane only
            m = fmaxf(m, z);
        }
        m = fmaxf(m, __shfl_xor(m, 1));
        m = fmaxf(m, __shfl_xor(m, 2));
        m = fmaxf(m, __shfl_xor(m, 4));

        float S = 0.0f;
        for (int k = sub; k < NK; k += 8) S += fast_exp(zr[k] - m);
        S += __shfl_xor(S, 1);
        S += __shfl_xor(S, 2);
        S += __shfl_xor(S, 4);
        float rS = __builtin_amdgcn_rcpf(S);

        // sentinel z_ext = sum_a wh[a]*tanh(ss+gh), split over the 8 lanes
        const float* sp = ssl + trow * 52;
        float ze = 0.0f;
        for (int a = sub; a < NA; a += 8) ze = fmaf(whl[a], fast_tanh(sp[a] + gp[a]), ze);
        ze += __shfl_xor(ze, 1);
        ze += __shfl_xor(ze, 2);
        ze += __shfl_xor(ze, 4);

        float m50  = fmaxf(m, ze);
        float eext = fast_exp(ze - m50);
        float beta = eext * __builtin_amdgcn_rcpf(S * fast_exp(m - m50) + eext);
        if (sub == 0) {
            betal[trow] = beta;
            out_beta[(size_t)b * NT + t0 + trow] = beta;
        }

        // alpha: own zl slots (k<49, LDS); bf16 A-frags (k<64, pad=0).
        // Global alpha deferred to the coalesced pass (R15 lesson).
        const int mt = trow >> 4, rr2 = trow & 15;
        for (int k = sub; k < 64; k += 8) {
            float a = (k < NK) ? fast_exp(zr[k] - m) * rS : 0.0f;
            if (k < NK) zr[k] = a;
            int ks = k >> 5, gg = (k & 31) >> 3;     // e = k&7 = sub
            afrag[(((ks * 2 + mt) * 64) + gg * 16 + rr2) * 8 + sub] = bf16rn(a);
        }
    }
    __syncthreads();   // barrier #2: zl(alpha)/afrag/betal ready

    // ---- alpha global write (contiguous fp32, from zl overlay)
    {
        float* oa = out_alpha + ((size_t)b * NT + t0) * NK;
        for (int idx = tid; idx < 32 * NK; idx += 256) {
            int t = (int)(((unsigned)idx * 1338u) >> 16);
            int k = idx - t * NK;
            oa[idx] = zl[t * 50 + k];
        }
    }

    // ---- phase D: c_t = alpha x V (single bf16), blend with s_t, store.
    // wave w owns ntiles 8w .. 8w+7 (128 h-cols).
    {
        const bf16x8* af = (const bf16x8*)afrag;
        const bf16x8* vb = (const bf16x8*)(VB + (size_t)b * 32768);
        const size_t rowb = (size_t)b * NT + t0;

        bf16x8 a00 = af[(0 * 2 + 0) * 64 + lane];   // [ks][mt]
        bf16x8 a01 = af[(0 * 2 + 1) * 64 + lane];
        bf16x8 a10 = af[(1 * 2 + 0) * 64 + lane];
        bf16x8 a11 = af[(1 * 2 + 1) * 64 + lane];

        #pragma unroll 2
        for (int ntl = 0; ntl < 8; ++ntl) {
            const int nt = w * 8 + ntl;
            bf16x8 b0 = vb[(nt * 2 + 0) * 64 + lane];
            bf16x8 b1 = vb[(nt * 2 + 1) * 64 + lane];
            f32x4 acc0 = {0.f, 0.f, 0.f, 0.f};
            f32x4 acc1 = acc0;
            acc0 = __builtin_amdgcn_mfma_f32_16x16x32_bf16(a00, b0, acc0, 0, 0, 0);
            acc0 = __builtin_amdgcn_mfma_f32_16x16x32_bf16(a10, b1, acc0, 0, 0, 0);
            acc1 = __builtin_amdgcn_mfma_f32_16x16x32_bf16(a01, b0, acc1, 0, 0, 0);
            acc1 = __builtin_amdgcn_mfma_f32_16x16x32_bf16(a11, b1, acc1, 0, 0, 0);

            const int h0 = nt * 16 + r;
            #pragma unroll
            for (int reg = 0; reg < 4; ++reg) {
                {   // mt 0
                    int tloc = g * 4 + reg;
                    float bt = betal[tloc];
                    size_t off = (rowb + tloc) * NH + h0;
                    float s = s_t[off];
                    out_chat[off] = fmaf(bt, s - acc0[reg], acc0[reg]);
                }
                {   // mt 1
                    int tloc = 16 + g * 4 + reg;
                    float bt = betal[tloc];
                    size_t off = (rowb + tloc) * NH + h0;
                    float s = s_t[off];
                    out_chat[off] = fmaf(bt, s - acc1[reg], acc1[reg]);
                }
            }
        }
    }
}

// ---------------------------------------------------------------------------
extern "C" void kernel_launch(void* const* d_in, const int* in_sizes, int n_in,
                              void* d_out, int out_size, void* d_ws, size_t ws_size,
                              hipStream_t stream) {
    const float* V   = (const float*)d_in[0];
    const float* h_t = (const float*)d_in[1];
    const float* s_t = (const float*)d_in[2];
    const float* Wv  = (const float*)d_in[3];
    const float* Wg  = (const float*)d_in[4];
    const float* Ws  = (const float*)d_in[5];
    const float* Wh  = (const float*)d_in[6];

    float* out = (float*)d_out;
    float* out_chat  = out;                                   // B*T*H
    float* out_alpha = out + (size_t)NB * NT * NH;            // B*T*K
    float* out_beta  = out_alpha + (size_t)NB * NT * NK;      // B*T

    // workspace: WB 3*65536 bf16 | VB 64*32768 bf16 | cv 3136*52 f32
    short* WB = (short*)d_ws;
    short* VB = WB + (size_t)3 * 65536;
    float* cv = (float*)(VB + (size_t)64 * 32768);

    kprew<<<24, 256, 0, stream>>>(Wg, Ws, Wv, WB);                 // WB producer
    kprev<<<561, 256, 0, stream>>>(V, WB, VB, cv);                 // VB + cv (reads WB)
    kfused<<<NB * 16, 256, 0, stream>>>(h_t, s_t, Wh, WB, VB, cv,
                                        out_chat, out_alpha, out_beta);
}

// Round 24
// 84.926 us; speedup vs baseline: 1.9463x; 1.9463x over previous
//
#include <hip/hip_runtime.h>
#include <hip/hip_bf16.h>
#include <cstdint>
#include <cstddef>

// Problem constants
#define NB 64
#define NK 49
#define NT 512
#define NH 512
#define NA 49

typedef __attribute__((ext_vector_type(8))) short bf16x8;
typedef __attribute__((ext_vector_type(4))) float f32x4;

__device__ __forceinline__ float fast_exp(float x) {            // e^x
    return __builtin_amdgcn_exp2f(x * 1.4426950408889634f);
}
__device__ __forceinline__ float fast_tanh(float x) {           // 1 - 2/(e^{2x}+1)
    float e = __builtin_amdgcn_exp2f(x * 2.8853900817779268f);
    return 1.0f - 2.0f * __builtin_amdgcn_rcpf(e + 1.0f);
}
__device__ __forceinline__ short bf16rn(float x) {              // round-to-nearest-even bf16
    unsigned b = __builtin_bit_cast(unsigned, x);
    unsigned r = b + 0x7FFFu + ((b >> 16) & 1u);
    return (short)(r >> 16);
}
__device__ __forceinline__ void split_hi_lo(float x, short& hi, short& lo) {
    unsigned b = __builtin_bit_cast(unsigned, x);
    unsigned hb = b & 0xFFFF0000u;
    hi = (short)(hb >> 16);
    lo = bf16rn(x - __builtin_bit_cast(float, hb));
}
__device__ __forceinline__ bf16x8 cvt8(float4 x0, float4 x1) {  // 8 f32 -> bf16 (rn)
    bf16x8 a;
    a[0] = bf16rn(x0.x); a[1] = bf16rn(x0.y); a[2] = bf16rn(x0.z); a[3] = bf16rn(x0.w);
    a[4] = bf16rn(x1.x); a[5] = bf16rn(x1.y); a[6] = bf16rn(x1.z); a[7] = bf16rn(x1.w);
    return a;
}

// ---------------------------------------------------------------------------
// kprew: weight swizzle (producer of WB; separate launch for ordering).
// WB[job][sel(hi/lo)][ntile(4)][kstep(16)][lane(64)][e(8)] (bf16)
// jobs 0/1: sel=0 is rn-rounded (single-term consumer in kfused).
// job 2:    sel=0 truncated hi, sel=1 lo (3-term consumer in kprev).
// ---------------------------------------------------------------------------
__global__ __launch_bounds__(256, 4) void kprew(
        const float* __restrict__ Wg, const float* __restrict__ Ws,
        const float* __restrict__ Wv, short* __restrict__ WB) {
    const int job = blockIdx.x >> 3, slice = blockIdx.x & 7;
    const float* W = (job == 0) ? Wg : (job == 1 ? Ws : Wv);
    short* dst = WB + (size_t)job * 65536;
    const int end = (slice + 1) * 8192;
    for (int idx = slice * 8192 + threadIdx.x; idx < end; idx += 256) {
        int e    = idx & 7;
        int lane = (idx >> 3) & 63;
        int ks   = (idx >> 9) & 15;
        int nt   = (idx >> 13) & 3;
        int sel  = idx >> 15;
        int a = nt * 16 + (lane & 15);
        int h = ks * 32 + (lane >> 4) * 8 + e;
        float x = (a < NA) ? W[a * NH + h] : 0.0f;
        short v;
        if (job < 2) {
            short hi, lo; split_hi_lo(x, hi, lo);
            v = sel ? lo : bf16rn(x);
        } else {
            short hi, lo; split_hi_lo(x, hi, lo);
            v = sel ? lo : hi;
        }
        dst[idx] = v;
    }
}

// ---------------------------------------------------------------------------
// kprev: blocks 0..511 = V frag swizzle; blocks 512..560 = cv GEMM (reads WB
// from previous launch; hi/lo 3-term kept for cv precision).
//  VB[b][ntile(32)][ks(2)][lane(64)][e(8)]; cv rows padded to 52 floats.
// ---------------------------------------------------------------------------
__global__ __launch_bounds__(256, 4) void kprev(
        const float* __restrict__ V, const short* __restrict__ WB,
        short* __restrict__ VB, float* __restrict__ cv) {
    const int bid = blockIdx.x;
    if (bid < 512) {
        __shared__ float vl[NK * 64];
        const int b  = bid >> 3;
        const int sl = bid & 7;
        const int h0 = sl * 64;
        const float* Vb = V + (size_t)b * (NK * NH);
        for (int idx = threadIdx.x; idx < NK * 64; idx += 256) {
            int k = idx >> 6, c = idx & 63;
            vl[idx] = Vb[(size_t)k * NH + h0 + c];
        }
        __syncthreads();
        short* dst = VB + (size_t)b * 32768;
        for (int idx = threadIdx.x; idx < 4096; idx += 256) {
            int e    = idx & 7;
            int lane = (idx >> 3) & 63;
            int ks   = (idx >> 9) & 1;
            int ntl  = idx >> 10;
            int k = ks * 32 + (lane >> 4) * 8 + e;
            int c = ntl * 16 + (lane & 15);
            float x = (k < NK) ? vl[k * 64 + c] : 0.0f;
            dst[((size_t)(sl * 4 + ntl) * 2 + ks) * 512 + lane * 8 + e] = bf16rn(x);
        }
    } else {
        const int tid  = threadIdx.x;
        const int lane = tid & 63;
        const int w    = tid >> 6;
        const int m0   = (bid - 512) * 64 + w * 16;
        const int r    = lane & 15;
        const int g    = lane >> 4;

        const float* arow = V + (size_t)(m0 + r) * NH + g * 8;
        const bf16x8* wbv = (const bf16x8*)(WB + 2 * 65536);

        f32x4 acc0 = {0.f, 0.f, 0.f, 0.f};
        f32x4 acc1 = acc0, acc2 = acc0, acc3 = acc0;

        #pragma unroll 2
        for (int ks = 0; ks < 16; ++ks) {
            float4 x0 = *(const float4*)(arow + ks * 32);
            float4 x1 = *(const float4*)(arow + ks * 32 + 4);
            bf16x8 bh0 = wbv[(0 * 16 + ks) * 64 + lane];
            bf16x8 bh1 = wbv[(1 * 16 + ks) * 64 + lane];
            bf16x8 bh2 = wbv[(2 * 16 + ks) * 64 + lane];
            bf16x8 bh3 = wbv[(3 * 16 + ks) * 64 + lane];
            bf16x8 bl0 = wbv[(4 * 16 + ks) * 64 + lane];
            bf16x8 bl1 = wbv[(5 * 16 + ks) * 64 + lane];
            bf16x8 bl2 = wbv[(6 * 16 + ks) * 64 + lane];
            bf16x8 bl3 = wbv[(7 * 16 + ks) * 64 + lane];

            bf16x8 ahi, alo;
            {
                const float xs[8] = {x0.x, x0.y, x0.z, x0.w, x1.x, x1.y, x1.z, x1.w};
                #pragma unroll
                for (int e = 0; e < 8; ++e) { short hi, lo; split_hi_lo(xs[e], hi, lo); ahi[e] = hi; alo[e] = lo; }
            }
            acc0 = __builtin_amdgcn_mfma_f32_16x16x32_bf16(ahi, bh0, acc0, 0, 0, 0);
            acc0 = __builtin_amdgcn_mfma_f32_16x16x32_bf16(alo, bh0, acc0, 0, 0, 0);
            acc0 = __builtin_amdgcn_mfma_f32_16x16x32_bf16(ahi, bl0, acc0, 0, 0, 0);
            acc1 = __builtin_amdgcn_mfma_f32_16x16x32_bf16(ahi, bh1, acc1, 0, 0, 0);
            acc1 = __builtin_amdgcn_mfma_f32_16x16x32_bf16(alo, bh1, acc1, 0, 0, 0);
            acc1 = __builtin_amdgcn_mfma_f32_16x16x32_bf16(ahi, bl1, acc1, 0, 0, 0);
            acc2 = __builtin_amdgcn_mfma_f32_16x16x32_bf16(ahi, bh2, acc2, 0, 0, 0);
            acc2 = __builtin_amdgcn_mfma_f32_16x16x32_bf16(alo, bh2, acc2, 0, 0, 0);
            acc2 = __builtin_amdgcn_mfma_f32_16x16x32_bf16(ahi, bl2, acc2, 0, 0, 0);
            acc3 = __builtin_amdgcn_mfma_f32_16x16x32_bf16(ahi, bh3, acc3, 0, 0, 0);
            acc3 = __builtin_amdgcn_mfma_f32_16x16x32_bf16(alo, bh3, acc3, 0, 0, 0);
            acc3 = __builtin_amdgcn_mfma_f32_16x16x32_bf16(ahi, bl3, acc3, 0, 0, 0);
        }

        #pragma unroll
        for (int reg = 0; reg < 4; ++reg) {
            int row = m0 + g * 4 + reg;
            float* orow = cv + (size_t)row * 52;
            orow[ 0 + r] = acc0[reg];
            orow[16 + r] = acc1[reg];
            orow[32 + r] = acc2[reg];
            if (r == 0) orow[48] = acc3[reg];
        }
    }
}

// ---------------------------------------------------------------------------
// kfused (R22 FINAL, 84.8us): one block per (b, 32-row t-tile). 256 threads
// = 4 waves. 1024 blocks. XCD-aware swizzle (T1: -17MB FETCH, +2us).
//  A) gh/ss MFMA GEMM -> LDS. SINGLE-bf16 A and B; ks-PAIR hoisted loads.
//  B) z[t][k] from LDS cvl; 4-partial tanh-dot (SEPARATE phase — fused BC
//     spills to scratch: R13/R15/R23 all showed +140MB FETCH)
//  C) wave-parallel softmax (8-lane groups) + cooperative sentinel z_ext
//  D) c_t = alpha x V (single-bf16 MFMA), blend with s_t, store
// launch_bounds(256,4) = 128 total VGPR (only non-spilling bound; R5/R8/
// R14/R18). No cross-phase register state (R13/R20). Coalesced alpha (R15).
// ---------------------------------------------------------------------------
__global__ __launch_bounds__(256, 4) void kfused(
        const float* __restrict__ h_t, const float* __restrict__ s_t,
        const float* __restrict__ Wh,
        const short* __restrict__ WB, const short* __restrict__ VB,
        const float* __restrict__ cv_ws,
        float* __restrict__ out_chat, float* __restrict__ out_alpha,
        float* __restrict__ out_beta) {
    __shared__ float cvl[NK * 52];       // 10,192 B (padded rows, direct copy)
    __shared__ float ghl[32 * 52];       //  6,656 B
    __shared__ float ssl[32 * 52];       //  6,656 B
    __shared__ float zl[32 * 50];        //  6,400 B ; alpha fp32 overlays
    __shared__ short afrag[2048];        //  4,096 B : [ks(2)][mt(2)][lane(64)][e(8)]
    __shared__ float whl[52];            //    208 B
    __shared__ float betal[32];          //    128 B

    const int tid  = threadIdx.x;
    const int lane = tid & 63;
    const int w    = tid >> 6;
    // XCD-aware swizzle: same-b blocks cluster on one XCD (L2 locality).
    const int bid  = ((blockIdx.x & 7) << 7) + (blockIdx.x >> 3);
    const int b    = bid >> 4;
    const int t0   = (bid & 15) * 32;
    const int r    = lane & 15;
    const int g    = lane >> 4;

    if (tid < NA) whl[tid] = Wh[tid];

    // ---- stage cv (padded-52 rows, contiguous coalesced copy)
    {
        const float* cvb = cv_ws + (size_t)b * (NK * 52);
        for (int idx = tid; idx < NK * 52; idx += 256) cvl[idx] = cvb[idx];
    }

    // ---- phase A: gh / ss GEMM, single-bf16 both sides, ks-pair hoisted.
    {
        const int job = w >> 1, mtile = w & 1;
        const float* in = job ? s_t : h_t;
        const bf16x8* wb = (const bf16x8*)(WB + (size_t)job * 65536);
        const float* arow = in + (size_t)(b * NT + t0 + mtile * 16 + r) * NH + g * 8;
        f32x4 acc0 = {0.f, 0.f, 0.f, 0.f};
        f32x4 acc1 = acc0, acc2 = acc0, acc3 = acc0;
        #pragma unroll 1
        for (int kp = 0; kp < 8; ++kp) {
            const int ksa = kp * 2, ksb = kp * 2 + 1;
            // ---- all loads for both ks of the pair issue first (MLP)
            float4 xa0 = *(const float4*)(arow + ksa * 32);
            float4 xa1 = *(const float4*)(arow + ksa * 32 + 4);
            float4 xb0 = *(const float4*)(arow + ksb * 32);
            float4 xb1 = *(const float4*)(arow + ksb * 32 + 4);
            bf16x8 b0a = wb[(0 * 16 + ksa) * 64 + lane];
            bf16x8 b1a = wb[(1 * 16 + ksa) * 64 + lane];
            bf16x8 b2a = wb[(2 * 16 + ksa) * 64 + lane];
            bf16x8 b3a = wb[(3 * 16 + ksa) * 64 + lane];
            bf16x8 b0b = wb[(0 * 16 + ksb) * 64 + lane];
            bf16x8 b1b = wb[(1 * 16 + ksb) * 64 + lane];
            bf16x8 b2b = wb[(2 * 16 + ksb) * 64 + lane];
            bf16x8 b3b = wb[(3 * 16 + ksb) * 64 + lane];

            bf16x8 aa = cvt8(xa0, xa1);
            acc0 = __builtin_amdgcn_mfma_f32_16x16x32_bf16(aa, b0a, acc0, 0, 0, 0);
            acc1 = __builtin_amdgcn_mfma_f32_16x16x32_bf16(aa, b1a, acc1, 0, 0, 0);
            acc2 = __builtin_amdgcn_mfma_f32_16x16x32_bf16(aa, b2a, acc2, 0, 0, 0);
            acc3 = __builtin_amdgcn_mfma_f32_16x16x32_bf16(aa, b3a, acc3, 0, 0, 0);

            bf16x8 ab = cvt8(xb0, xb1);
            acc0 = __builtin_amdgcn_mfma_f32_16x16x32_bf16(ab, b0b, acc0, 0, 0, 0);
            acc1 = __builtin_amdgcn_mfma_f32_16x16x32_bf16(ab, b1b, acc1, 0, 0, 0);
            acc2 = __builtin_amdgcn_mfma_f32_16x16x32_bf16(ab, b2b, acc2, 0, 0, 0);
            acc3 = __builtin_amdgcn_mfma_f32_16x16x32_bf16(ab, b3b, acc3, 0, 0, 0);
        }
        float* dst = (w >> 1) ? ssl : ghl;
        #pragma unroll
        for (int reg = 0; reg < 4; ++reg) {
            int m = mtile * 16 + g * 4 + reg;
            dst[m * 52 +  0 + r] = acc0[reg];
            dst[m * 52 + 16 + r] = acc1[reg];
            dst[m * 52 + 32 + r] = acc2[reg];
            if (r < 4) dst[m * 52 + 48 + r] = acc3[reg];  // only col 48 used downstream
        }
    }
    __syncthreads();

    // ---- phase B: z[t][k], k<49 only, from LDS. 4 independent partial sums.
    {
        for (int p = tid; p < 32 * NK; p += 256) {
            int t = (int)(((unsigned)p * 1338u) >> 16);   // p/49 for p<2520
            int k = p - t * NK;
            const float* rowp = cvl + k * 52;
            const float* gp   = ghl + t * 52;
            float zx = 0.f, zy = 0.f, zz = 0.f, zw = 0.f;
            #pragma unroll
            for (int q = 0; q < 12; ++q) {
                float4 rr = *(const float4*)(rowp + q * 4);
                float4 gg = *(const float4*)(gp + q * 4);
                zx = fmaf(whl[q * 4 + 0], fast_tanh(rr.x + gg.x), zx);
                zy = fmaf(whl[q * 4 + 1], fast_tanh(rr.y + gg.y), zy);
                zz = fmaf(whl[q * 4 + 2], fast_tanh(rr.z + gg.z), zz);
                zw = fmaf(whl[q * 4 + 3], fast_tanh(rr.w + gg.w), zw);
            }
            float z = (zx + zy) + (zz + zw);
            zl[t * 50 + k] = fmaf(whl[48], fast_tanh(rowp[48] + gp[48]), z);
        }
    }
    __syncthreads();

    // ---- phase C: wave-parallel softmax. trow = 8w + (lane>>3), sub = lane&7.
    {
        const int trow = w * 8 + (lane >> 3);
        const int sub  = lane & 7;
        float* zr = zl + trow * 50;

        float m = -1e30f;
        for (int k = sub; k < NK; k += 8) m = fmaxf(m, zr[k]);
        m = fmaxf(m, __shfl_xor(m, 1));
        m = fmaxf(m, __shfl_xor(m, 2));
        m = fmaxf(m, __shfl_xor(m, 4));

        float S = 0.0f;
        for (int k = sub; k < NK; k += 8) S += fast_exp(zr[k] - m);
        S += __shfl_xor(S, 1);
        S += __shfl_xor(S, 2);
        S += __shfl_xor(S, 4);
        float rS = __builtin_amdgcn_rcpf(S);

        // sentinel z_ext = sum_a wh[a]*tanh(ss+gh), split over the 8 lanes
        const float* sp = ssl + trow * 52;
        const float* gp = ghl + trow * 52;
        float ze = 0.0f;
        for (int a = sub; a < NA; a += 8) ze = fmaf(whl[a], fast_tanh(sp[a] + gp[a]), ze);
        ze += __shfl_xor(ze, 1);
        ze += __shfl_xor(ze, 2);
        ze += __shfl_xor(ze, 4);

        float m50  = fmaxf(m, ze);
        float eext = fast_exp(ze - m50);
        float beta = eext * __builtin_amdgcn_rcpf(S * fast_exp(m - m50) + eext);
        if (sub == 0) {
            betal[trow] = beta;
            out_beta[(size_t)b * NT + t0 + trow] = beta;
        }

        // alpha: own zl slots (k<49); bf16 A-frags (k<64, pad=0 -> all slots)
        const int mt = trow >> 4, rr2 = trow & 15;
        for (int k = sub; k < 64; k += 8) {
            float a = (k < NK) ? fast_exp(zr[k] - m) * rS : 0.0f;
            if (k < NK) zr[k] = a;
            int ks = k >> 5, gg = (k & 31) >> 3;     // e = k&7 = sub
            afrag[(((ks * 2 + mt) * 64) + gg * 16 + rr2) * 8 + sub] = bf16rn(a);
        }
    }
    __syncthreads();

    // ---- alpha global write (contiguous fp32, from zl overlay)
    {
        float* oa = out_alpha + ((size_t)b * NT + t0) * NK;
        for (int idx = tid; idx < 32 * NK; idx += 256) {
            int t = (int)(((unsigned)idx * 1338u) >> 16);
            int k = idx - t * NK;
            oa[idx] = zl[t * 50 + k];
        }
    }

    // ---- phase D: c_t = alpha x V (single bf16), blend with s_t, store.
    // wave w owns ntiles 8w .. 8w+7 (128 h-cols).
    {
        const bf16x8* af = (const bf16x8*)afrag;
        const bf16x8* vb = (const bf16x8*)(VB + (size_t)b * 32768);
        const size_t rowb = (size_t)b * NT + t0;

        bf16x8 a00 = af[(0 * 2 + 0) * 64 + lane];   // [ks][mt]
        bf16x8 a01 = af[(0 * 2 + 1) * 64 + lane];
        bf16x8 a10 = af[(1 * 2 + 0) * 64 + lane];
        bf16x8 a11 = af[(1 * 2 + 1) * 64 + lane];

        #pragma unroll 2
        for (int ntl = 0; ntl < 8; ++ntl) {
            const int nt = w * 8 + ntl;
            bf16x8 b0 = vb[(nt * 2 + 0) * 64 + lane];
            bf16x8 b1 = vb[(nt * 2 + 1) * 64 + lane];
            f32x4 acc0 = {0.f, 0.f, 0.f, 0.f};
            f32x4 acc1 = acc0;
            acc0 = __builtin_amdgcn_mfma_f32_16x16x32_bf16(a00, b0, acc0, 0, 0, 0);
            acc0 = __builtin_amdgcn_mfma_f32_16x16x32_bf16(a10, b1, acc0, 0, 0, 0);
            acc1 = __builtin_amdgcn_mfma_f32_16x16x32_bf16(a01, b0, acc1, 0, 0, 0);
            acc1 = __builtin_amdgcn_mfma_f32_16x16x32_bf16(a11, b1, acc1, 0, 0, 0);

            const int h0 = nt * 16 + r;
            #pragma unroll
            for (int reg = 0; reg < 4; ++reg) {
                {   // mt 0
                    int tloc = g * 4 + reg;
                    float bt = betal[tloc];
                    size_t off = (rowb + tloc) * NH + h0;
                    float s = s_t[off];
                    out_chat[off] = fmaf(bt, s - acc0[reg], acc0[reg]);
                }
                {   // mt 1
                    int tloc = 16 + g * 4 + reg;
                    float bt = betal[tloc];
                    size_t off = (rowb + tloc) * NH + h0;
                    float s = s_t[off];
                    out_chat[off] = fmaf(bt, s - acc1[reg], acc1[reg]);
                }
            }
        }
    }
}

// ---------------------------------------------------------------------------
extern "C" void kernel_launch(void* const* d_in, const int* in_sizes, int n_in,
                              void* d_out, int out_size, void* d_ws, size_t ws_size,
                              hipStream_t stream) {
    const float* V   = (const float*)d_in[0];
    const float* h_t = (const float*)d_in[1];
    const float* s_t = (const float*)d_in[2];
    const float* Wv  = (const float*)d_in[3];
    const float* Wg  = (const float*)d_in[4];
    const float* Ws  = (const float*)d_in[5];
    const float* Wh  = (const float*)d_in[6];

    float* out = (float*)d_out;
    float* out_chat  = out;                                   // B*T*H
    float* out_alpha = out + (size_t)NB * NT * NH;            // B*T*K
    float* out_beta  = out_alpha + (size_t)NB * NT * NK;      // B*T

    // workspace: WB 3*65536 bf16 | VB 64*32768 bf16 | cv 3136*52 f32
    short* WB = (short*)d_ws;
    short* VB = WB + (size_t)3 * 65536;
    float* cv = (float*)(VB + (size_t)64 * 32768);

    kprew<<<24, 256, 0, stream>>>(Wg, Ws, Wv, WB);                 // WB producer
    kprev<<<561, 256, 0, stream>>>(V, WB, VB, cv);                 // VB + cv (reads WB)
    kfused<<<NB * 16, 256, 0, stream>>>(h_t, s_t, Wh, WB, VB, cv,
                                        out_chat, out_alpha, out_beta);
}

// Round 25
// 84.651 us; speedup vs baseline: 1.9527x; 1.0033x over previous
//
#include <hip/hip_runtime.h>
#include <hip/hip_bf16.h>
#include <cstdint>
#include <cstddef>

// Problem constants
#define NB 64
#define NK 49
#define NT 512
#define NH 512
#define NA 49

typedef __attribute__((ext_vector_type(8))) short bf16x8;
typedef __attribute__((ext_vector_type(4))) float f32x4;

__device__ __forceinline__ float fast_exp(float x) {            // e^x
    return __builtin_amdgcn_exp2f(x * 1.4426950408889634f);
}
__device__ __forceinline__ float fast_tanh(float x) {           // 1 - 2/(e^{2x}+1)
    float e = __builtin_amdgcn_exp2f(x * 2.8853900817779268f);
    return 1.0f - 2.0f * __builtin_amdgcn_rcpf(e + 1.0f);
}
__device__ __forceinline__ short bf16rn(float x) {              // round-to-nearest-even bf16
    unsigned b = __builtin_bit_cast(unsigned, x);
    unsigned r = b + 0x7FFFu + ((b >> 16) & 1u);
    return (short)(r >> 16);
}
__device__ __forceinline__ void split_hi_lo(float x, short& hi, short& lo) {
    unsigned b = __builtin_bit_cast(unsigned, x);
    unsigned hb = b & 0xFFFF0000u;
    hi = (short)(hb >> 16);
    lo = bf16rn(x - __builtin_bit_cast(float, hb));
}
__device__ __forceinline__ bf16x8 cvt8(float4 x0, float4 x1) {  // 8 f32 -> bf16 (rn)
    bf16x8 a;
    a[0] = bf16rn(x0.x); a[1] = bf16rn(x0.y); a[2] = bf16rn(x0.z); a[3] = bf16rn(x0.w);
    a[4] = bf16rn(x1.x); a[5] = bf16rn(x1.y); a[6] = bf16rn(x1.z); a[7] = bf16rn(x1.w);
    return a;
}

// ---------------------------------------------------------------------------
// kprew: weight swizzle (producer of WB; separate launch for ordering).
// WB[job][sel(hi/lo)][ntile(4)][kstep(16)][lane(64)][e(8)] (bf16)
// jobs 0/1: sel=0 is rn-rounded (single-term consumer in kfused).
// job 2:    sel=0 truncated hi, sel=1 lo (3-term consumer in kprev).
// ---------------------------------------------------------------------------
__global__ __launch_bounds__(256, 4) void kprew(
        const float* __restrict__ Wg, const float* __restrict__ Ws,
        const float* __restrict__ Wv, short* __restrict__ WB) {
    const int job = blockIdx.x >> 3, slice = blockIdx.x & 7;
    const float* W = (job == 0) ? Wg : (job == 1 ? Ws : Wv);
    short* dst = WB + (size_t)job * 65536;
    const int end = (slice + 1) * 8192;
    for (int idx = slice * 8192 + threadIdx.x; idx < end; idx += 256) {
        int e    = idx & 7;
        int lane = (idx >> 3) & 63;
        int ks   = (idx >> 9) & 15;
        int nt   = (idx >> 13) & 3;
        int sel  = idx >> 15;
        int a = nt * 16 + (lane & 15);
        int h = ks * 32 + (lane >> 4) * 8 + e;
        float x = (a < NA) ? W[a * NH + h] : 0.0f;
        short v;
        if (job < 2) {
            short hi, lo; split_hi_lo(x, hi, lo);
            v = sel ? lo : bf16rn(x);
        } else {
            short hi, lo; split_hi_lo(x, hi, lo);
            v = sel ? lo : hi;
        }
        dst[idx] = v;
    }
}

// ---------------------------------------------------------------------------
// kprev: blocks 0..511 = V frag swizzle; blocks 512..560 = cv GEMM (reads WB
// from previous launch; hi/lo 3-term kept for cv precision).
//  VB[b][ntile(32)][ks(2)][lane(64)][e(8)]; cv rows padded to 52 floats.
// ---------------------------------------------------------------------------
__global__ __launch_bounds__(256, 4) void kprev(
        const float* __restrict__ V, const short* __restrict__ WB,
        short* __restrict__ VB, float* __restrict__ cv) {
    const int bid = blockIdx.x;
    if (bid < 512) {
        __shared__ float vl[NK * 64];
        const int b  = bid >> 3;
        const int sl = bid & 7;
        const int h0 = sl * 64;
        const float* Vb = V + (size_t)b * (NK * NH);
        for (int idx = threadIdx.x; idx < NK * 64; idx += 256) {
            int k = idx >> 6, c = idx & 63;
            vl[idx] = Vb[(size_t)k * NH + h0 + c];
        }
        __syncthreads();
        short* dst = VB + (size_t)b * 32768;
        for (int idx = threadIdx.x; idx < 4096; idx += 256) {
            int e    = idx & 7;
            int lane = (idx >> 3) & 63;
            int ks   = (idx >> 9) & 1;
            int ntl  = idx >> 10;
            int k = ks * 32 + (lane >> 4) * 8 + e;
            int c = ntl * 16 + (lane & 15);
            float x = (k < NK) ? vl[k * 64 + c] : 0.0f;
            dst[((size_t)(sl * 4 + ntl) * 2 + ks) * 512 + lane * 8 + e] = bf16rn(x);
        }
    } else {
        const int tid  = threadIdx.x;
        const int lane = tid & 63;
        const int w    = tid >> 6;
        const int m0   = (bid - 512) * 64 + w * 16;
        const int r    = lane & 15;
        const int g    = lane >> 4;

        const float* arow = V + (size_t)(m0 + r) * NH + g * 8;
        const bf16x8* wbv = (const bf16x8*)(WB + 2 * 65536);

        f32x4 acc0 = {0.f, 0.f, 0.f, 0.f};
        f32x4 acc1 = acc0, acc2 = acc0, acc3 = acc0;

        #pragma unroll 2
        for (int ks = 0; ks < 16; ++ks) {
            float4 x0 = *(const float4*)(arow + ks * 32);
            float4 x1 = *(const float4*)(arow + ks * 32 + 4);
            bf16x8 bh0 = wbv[(0 * 16 + ks) * 64 + lane];
            bf16x8 bh1 = wbv[(1 * 16 + ks) * 64 + lane];
            bf16x8 bh2 = wbv[(2 * 16 + ks) * 64 + lane];
            bf16x8 bh3 = wbv[(3 * 16 + ks) * 64 + lane];
            bf16x8 bl0 = wbv[(4 * 16 + ks) * 64 + lane];
            bf16x8 bl1 = wbv[(5 * 16 + ks) * 64 + lane];
            bf16x8 bl2 = wbv[(6 * 16 + ks) * 64 + lane];
            bf16x8 bl3 = wbv[(7 * 16 + ks) * 64 + lane];

            bf16x8 ahi, alo;
            {
                const float xs[8] = {x0.x, x0.y, x0.z, x0.w, x1.x, x1.y, x1.z, x1.w};
                #pragma unroll
                for (int e = 0; e < 8; ++e) { short hi, lo; split_hi_lo(xs[e], hi, lo); ahi[e] = hi; alo[e] = lo; }
            }
            acc0 = __builtin_amdgcn_mfma_f32_16x16x32_bf16(ahi, bh0, acc0, 0, 0, 0);
            acc0 = __builtin_amdgcn_mfma_f32_16x16x32_bf16(alo, bh0, acc0, 0, 0, 0);
            acc0 = __builtin_amdgcn_mfma_f32_16x16x32_bf16(ahi, bl0, acc0, 0, 0, 0);
            acc1 = __builtin_amdgcn_mfma_f32_16x16x32_bf16(ahi, bh1, acc1, 0, 0, 0);
            acc1 = __builtin_amdgcn_mfma_f32_16x16x32_bf16(alo, bh1, acc1, 0, 0, 0);
            acc1 = __builtin_amdgcn_mfma_f32_16x16x32_bf16(ahi, bl1, acc1, 0, 0, 0);
            acc2 = __builtin_amdgcn_mfma_f32_16x16x32_bf16(ahi, bh2, acc2, 0, 0, 0);
            acc2 = __builtin_amdgcn_mfma_f32_16x16x32_bf16(alo, bh2, acc2, 0, 0, 0);
            acc2 = __builtin_amdgcn_mfma_f32_16x16x32_bf16(ahi, bl2, acc2, 0, 0, 0);
            acc3 = __builtin_amdgcn_mfma_f32_16x16x32_bf16(ahi, bh3, acc3, 0, 0, 0);
            acc3 = __builtin_amdgcn_mfma_f32_16x16x32_bf16(alo, bh3, acc3, 0, 0, 0);
            acc3 = __builtin_amdgcn_mfma_f32_16x16x32_bf16(ahi, bl3, acc3, 0, 0, 0);
        }

        #pragma unroll
        for (int reg = 0; reg < 4; ++reg) {
            int row = m0 + g * 4 + reg;
            float* orow = cv + (size_t)row * 52;
            orow[ 0 + r] = acc0[reg];
            orow[16 + r] = acc1[reg];
            orow[32 + r] = acc2[reg];
            if (r == 0) orow[48] = acc3[reg];
        }
    }
}

// ---------------------------------------------------------------------------
// kfused (R22 FINAL, 84.8us): one block per (b, 32-row t-tile). 256 threads
// = 4 waves. 1024 blocks. XCD-aware swizzle (T1: -17MB FETCH, +2us).
//  A) gh/ss MFMA GEMM -> LDS. SINGLE-bf16 A and B; ks-PAIR hoisted loads.
//  B) z[t][k] from LDS cvl; 4-partial tanh-dot (SEPARATE phase — fused BC
//     spills to scratch: R13/R15/R23 all showed +140MB FETCH)
//  C) wave-parallel softmax (8-lane groups) + cooperative sentinel z_ext
//  D) c_t = alpha x V (single-bf16 MFMA), blend with s_t, store
// launch_bounds(256,4) = 128 total VGPR (only non-spilling bound; R5/R8/
// R14/R18). No cross-phase register state (R13/R20). Coalesced alpha (R15).
// ---------------------------------------------------------------------------
__global__ __launch_bounds__(256, 4) void kfused(
        const float* __restrict__ h_t, const float* __restrict__ s_t,
        const float* __restrict__ Wh,
        const short* __restrict__ WB, const short* __restrict__ VB,
        const float* __restrict__ cv_ws,
        float* __restrict__ out_chat, float* __restrict__ out_alpha,
        float* __restrict__ out_beta) {
    __shared__ float cvl[NK * 52];       // 10,192 B (padded rows, direct copy)
    __shared__ float ghl[32 * 52];       //  6,656 B
    __shared__ float ssl[32 * 52];       //  6,656 B
    __shared__ float zl[32 * 50];        //  6,400 B ; alpha fp32 overlays
    __shared__ short afrag[2048];        //  4,096 B : [ks(2)][mt(2)][lane(64)][e(8)]
    __shared__ float whl[52];            //    208 B
    __shared__ float betal[32];          //    128 B

    const int tid  = threadIdx.x;
    const int lane = tid & 63;
    const int w    = tid >> 6;
    // XCD-aware swizzle: same-b blocks cluster on one XCD (L2 locality).
    const int bid  = ((blockIdx.x & 7) << 7) + (blockIdx.x >> 3);
    const int b    = bid >> 4;
    const int t0   = (bid & 15) * 32;
    const int r    = lane & 15;
    const int g    = lane >> 4;

    if (tid < NA) whl[tid] = Wh[tid];

    // ---- stage cv (padded-52 rows, contiguous coalesced copy)
    {
        const float* cvb = cv_ws + (size_t)b * (NK * 52);
        for (int idx = tid; idx < NK * 52; idx += 256) cvl[idx] = cvb[idx];
    }

    // ---- phase A: gh / ss GEMM, single-bf16 both sides, ks-pair hoisted.
    {
        const int job = w >> 1, mtile = w & 1;
        const float* in = job ? s_t : h_t;
        const bf16x8* wb = (const bf16x8*)(WB + (size_t)job * 65536);
        const float* arow = in + (size_t)(b * NT + t0 + mtile * 16 + r) * NH + g * 8;
        f32x4 acc0 = {0.f, 0.f, 0.f, 0.f};
        f32x4 acc1 = acc0, acc2 = acc0, acc3 = acc0;
        #pragma unroll 1
        for (int kp = 0; kp < 8; ++kp) {
            const int ksa = kp * 2, ksb = kp * 2 + 1;
            // ---- all loads for both ks of the pair issue first (MLP)
            float4 xa0 = *(const float4*)(arow + ksa * 32);
            float4 xa1 = *(const float4*)(arow + ksa * 32 + 4);
            float4 xb0 = *(const float4*)(arow + ksb * 32);
            float4 xb1 = *(const float4*)(arow + ksb * 32 + 4);
            bf16x8 b0a = wb[(0 * 16 + ksa) * 64 + lane];
            bf16x8 b1a = wb[(1 * 16 + ksa) * 64 + lane];
            bf16x8 b2a = wb[(2 * 16 + ksa) * 64 + lane];
            bf16x8 b3a = wb[(3 * 16 + ksa) * 64 + lane];
            bf16x8 b0b = wb[(0 * 16 + ksb) * 64 + lane];
            bf16x8 b1b = wb[(1 * 16 + ksb) * 64 + lane];
            bf16x8 b2b = wb[(2 * 16 + ksb) * 64 + lane];
            bf16x8 b3b = wb[(3 * 16 + ksb) * 64 + lane];

            bf16x8 aa = cvt8(xa0, xa1);
            acc0 = __builtin_amdgcn_mfma_f32_16x16x32_bf16(aa, b0a, acc0, 0, 0, 0);
            acc1 = __builtin_amdgcn_mfma_f32_16x16x32_bf16(aa, b1a, acc1, 0, 0, 0);
            acc2 = __builtin_amdgcn_mfma_f32_16x16x32_bf16(aa, b2a, acc2, 0, 0, 0);
            acc3 = __builtin_amdgcn_mfma_f32_16x16x32_bf16(aa, b3a, acc3, 0, 0, 0);

            bf16x8 ab = cvt8(xb0, xb1);
            acc0 = __builtin_amdgcn_mfma_f32_16x16x32_bf16(ab, b0b, acc0, 0, 0, 0);
            acc1 = __builtin_amdgcn_mfma_f32_16x16x32_bf16(ab, b1b, acc1, 0, 0, 0);
            acc2 = __builtin_amdgcn_mfma_f32_16x16x32_bf16(ab, b2b, acc2, 0, 0, 0);
            acc3 = __builtin_amdgcn_mfma_f32_16x16x32_bf16(ab, b3b, acc3, 0, 0, 0);
        }
        float* dst = (w >> 1) ? ssl : ghl;
        #pragma unroll
        for (int reg = 0; reg < 4; ++reg) {
            int m = mtile * 16 + g * 4 + reg;
            dst[m * 52 +  0 + r] = acc0[reg];
            dst[m * 52 + 16 + r] = acc1[reg];
            dst[m * 52 + 32 + r] = acc2[reg];
            if (r < 4) dst[m * 52 + 48 + r] = acc3[reg];  // only col 48 used downstream
        }
    }
    __syncthreads();

    // ---- phase B: z[t][k], k<49 only, from LDS. 4 independent partial sums.
    {
        for (int p = tid; p < 32 * NK; p += 256) {
            int t = (int)(((unsigned)p * 1338u) >> 16);   // p/49 for p<2520
            int k = p - t * NK;
            const float* rowp = cvl + k * 52;
            const float* gp   = ghl + t * 52;
            float zx = 0.f, zy = 0.f, zz = 0.f, zw = 0.f;
            #pragma unroll
            for (int q = 0; q < 12; ++q) {
                float4 rr = *(const float4*)(rowp + q * 4);
                float4 gg = *(const float4*)(gp + q * 4);
                zx = fmaf(whl[q * 4 + 0], fast_tanh(rr.x + gg.x), zx);
                zy = fmaf(whl[q * 4 + 1], fast_tanh(rr.y + gg.y), zy);
                zz = fmaf(whl[q * 4 + 2], fast_tanh(rr.z + gg.z), zz);
                zw = fmaf(whl[q * 4 + 3], fast_tanh(rr.w + gg.w), zw);
            }
            float z = (zx + zy) + (zz + zw);
            zl[t * 50 + k] = fmaf(whl[48], fast_tanh(rowp[48] + gp[48]), z);
        }
    }
    __syncthreads();

    // ---- phase C: wave-parallel softmax. trow = 8w + (lane>>3), sub = lane&7.
    {
        const int trow = w * 8 + (lane >> 3);
        const int sub  = lane & 7;
        float* zr = zl + trow * 50;

        float m = -1e30f;
        for (int k = sub; k < NK; k += 8) m = fmaxf(m, zr[k]);
        m = fmaxf(m, __shfl_xor(m, 1));
        m = fmaxf(m, __shfl_xor(m, 2));
        m = fmaxf(m, __shfl_xor(m, 4));

        float S = 0.0f;
        for (int k = sub; k < NK; k += 8) S += fast_exp(zr[k] - m);
        S += __shfl_xor(S, 1);
        S += __shfl_xor(S, 2);
        S += __shfl_xor(S, 4);
        float rS = __builtin_amdgcn_rcpf(S);

        // sentinel z_ext = sum_a wh[a]*tanh(ss+gh), split over the 8 lanes
        const float* sp = ssl + trow * 52;
        const float* gp = ghl + trow * 52;
        float ze = 0.0f;
        for (int a = sub; a < NA; a += 8) ze = fmaf(whl[a], fast_tanh(sp[a] + gp[a]), ze);
        ze += __shfl_xor(ze, 1);
        ze += __shfl_xor(ze, 2);
        ze += __shfl_xor(ze, 4);

        float m50  = fmaxf(m, ze);
        float eext = fast_exp(ze - m50);
        float beta = eext * __builtin_amdgcn_rcpf(S * fast_exp(m - m50) + eext);
        if (sub == 0) {
            betal[trow] = beta;
            out_beta[(size_t)b * NT + t0 + trow] = beta;
        }

        // alpha: own zl slots (k<49); bf16 A-frags (k<64, pad=0 -> all slots)
        const int mt = trow >> 4, rr2 = trow & 15;
        for (int k = sub; k < 64; k += 8) {
            float a = (k < NK) ? fast_exp(zr[k] - m) * rS : 0.0f;
            if (k < NK) zr[k] = a;
            int ks = k >> 5, gg = (k & 31) >> 3;     // e = k&7 = sub
            afrag[(((ks * 2 + mt) * 64) + gg * 16 + rr2) * 8 + sub] = bf16rn(a);
        }
    }
    __syncthreads();

    // ---- alpha global write (contiguous fp32, from zl overlay)
    {
        float* oa = out_alpha + ((size_t)b * NT + t0) * NK;
        for (int idx = tid; idx < 32 * NK; idx += 256) {
            int t = (int)(((unsigned)idx * 1338u) >> 16);
            int k = idx - t * NK;
            oa[idx] = zl[t * 50 + k];
        }
    }

    // ---- phase D: c_t = alpha x V (single bf16), blend with s_t, store.
    // wave w owns ntiles 8w .. 8w+7 (128 h-cols).
    {
        const bf16x8* af = (const bf16x8*)afrag;
        const bf16x8* vb = (const bf16x8*)(VB + (size_t)b * 32768);
        const size_t rowb = (size_t)b * NT + t0;

        bf16x8 a00 = af[(0 * 2 + 0) * 64 + lane];   // [ks][mt]
        bf16x8 a01 = af[(0 * 2 + 1) * 64 + lane];
        bf16x8 a10 = af[(1 * 2 + 0) * 64 + lane];
        bf16x8 a11 = af[(1 * 2 + 1) * 64 + lane];

        #pragma unroll 2
        for (int ntl = 0; ntl < 8; ++ntl) {
            const int nt = w * 8 + ntl;
            bf16x8 b0 = vb[(nt * 2 + 0) * 64 + lane];
            bf16x8 b1 = vb[(nt * 2 + 1) * 64 + lane];
            f32x4 acc0 = {0.f, 0.f, 0.f, 0.f};
            f32x4 acc1 = acc0;
            acc0 = __builtin_amdgcn_mfma_f32_16x16x32_bf16(a00, b0, acc0, 0, 0, 0);
            acc0 = __builtin_amdgcn_mfma_f32_16x16x32_bf16(a10, b1, acc0, 0, 0, 0);
            acc1 = __builtin_amdgcn_mfma_f32_16x16x32_bf16(a01, b0, acc1, 0, 0, 0);
            acc1 = __builtin_amdgcn_mfma_f32_16x16x32_bf16(a11, b1, acc1, 0, 0, 0);

            const int h0 = nt * 16 + r;
            #pragma unroll
            for (int reg = 0; reg < 4; ++reg) {
                {   // mt 0
                    int tloc = g * 4 + reg;
                    float bt = betal[tloc];
                    size_t off = (rowb + tloc) * NH + h0;
                    float s = s_t[off];
                    out_chat[off] = fmaf(bt, s - acc0[reg], acc0[reg]);
                }
                {   // mt 1
                    int tloc = 16 + g * 4 + reg;
                    float bt = betal[tloc];
                    size_t off = (rowb + tloc) * NH + h0;
                    float s = s_t[off];
                    out_chat[off] = fmaf(bt, s - acc1[reg], acc1[reg]);
                }
            }
        }
    }
}

// ---------------------------------------------------------------------------
extern "C" void kernel_launch(void* const* d_in, const int* in_sizes, int n_in,
                              void* d_out, int out_size, void* d_ws, size_t ws_size,
                              hipStream_t stream) {
    const float* V   = (const float*)d_in[0];
    const float* h_t = (const float*)d_in[1];
    const float* s_t = (const float*)d_in[2];
    const float* Wv  = (const float*)d_in[3];
    const float* Wg  = (const float*)d_in[4];
    const float* Ws  = (const float*)d_in[5];
    const float* Wh  = (const float*)d_in[6];

    float* out = (float*)d_out;
    float* out_chat  = out;                                   // B*T*H
    float* out_alpha = out + (size_t)NB * NT * NH;            // B*T*K
    float* out_beta  = out_alpha + (size_t)NB * NT * NK;      // B*T

    // workspace: WB 3*65536 bf16 | VB 64*32768 bf16 | cv 3136*52 f32
    short* WB = (short*)d_ws;
    short* VB = WB + (size_t)3 * 65536;
    float* cv = (float*)(VB + (size_t)64 * 32768);

    kprew<<<24, 256, 0, stream>>>(Wg, Ws, Wv, WB);                 // WB producer
    kprev<<<561, 256, 0, stream>>>(V, WB, VB, cv);                 // VB + cv (reads WB)
    kfused<<<NB * 16, 256, 0, stream>>>(h_t, s_t, Wh, WB, VB, cv,
                                        out_chat, out_alpha, out_beta);
}